// Round 2
// baseline (533.479 us; speedup 1.0000x reference)
//
#include <hip/hip_runtime.h>

#define CMID 32
#define CIN 128
#define HNB 32
#define KP 15
#define NEG 0.1f
#define EPS 1e-5f

// ---------------------------------------------------------------------------
// K1: y1 = s_feats @ w_u1  (M x 128 @ 128 x 32) + per-channel sum/sumsq stats.
// Register-blocked: each thread computes 4 rows x 1 col, float4 LDS A-reads.
// ---------------------------------------------------------------------------
__global__ __launch_bounds__(256) void k1_gemm1(
    const float* __restrict__ A,   // s_feats (M,128)
    const float* __restrict__ B,   // w_u1 (128,32)
    float* __restrict__ y1,        // (M,32)
    float* __restrict__ st,        // stats: [0:32) sum, [32:64) sumsq
    int M)
{
    __shared__ float Bs[CIN * CMID];   // [j][c] 16 KB
    __shared__ float As[32 * CIN];     // 16 KB
    __shared__ float rsum[32], rsq[32];
    int t = threadIdx.x;
    for (int i = t; i < CIN * CMID; i += 256) Bs[i] = B[i];
    if (t < 32) { rsum[t] = 0.f; rsq[t] = 0.f; }
    int m0 = blockIdx.x * 32;
    int rows = min(32, M - m0);
    for (int i = t; i < rows * CIN; i += 256) As[i] = A[(size_t)m0 * CIN + i];
    __syncthreads();

    int c = t & 31;
    int rb = (t >> 5) * 4;
    float acc[4] = {0.f, 0.f, 0.f, 0.f};
    for (int j4 = 0; j4 < 32; ++j4) {
        float bv[4];
#pragma unroll
        for (int u = 0; u < 4; ++u) bv[u] = Bs[(j4 * 4 + u) * CMID + c];
#pragma unroll
        for (int i = 0; i < 4; ++i) {
            float4 a4 = *(const float4*)&As[(rb + i) * CIN + j4 * 4];
            acc[i] += a4.x * bv[0] + a4.y * bv[1] + a4.z * bv[2] + a4.w * bv[3];
        }
    }
    float lsum = 0.f, lsq = 0.f;
#pragma unroll
    for (int i = 0; i < 4; ++i) {
        if (rb + i < rows) {
            y1[(size_t)(m0 + rb + i) * CMID + c] = acc[i];
            lsum += acc[i]; lsq += acc[i] * acc[i];
        }
    }
    atomicAdd(&rsum[c], lsum); atomicAdd(&rsq[c], lsq);
    __syncthreads();
    if (t < 32) { atomicAdd(&st[t], rsum[t]); atomicAdd(&st[32 + t], rsq[t]); }
}

// ---------------------------------------------------------------------------
// K3: KPInv conv. One wave per point; lane = p*32 + c (p = half, c = channel).
// Each lane accumulates over 16 neighbors (h = 2*i+p) in registers; the only
// cross-lane shuffles are one xor-32 for the max and one for the final sum.
// Tiny MLP + per-neighbor s[h][g] go through per-wave LDS scratch.
// Fused: per-channel sum/sumsq stats of x2 (was k4).
// ---------------------------------------------------------------------------
__global__ __launch_bounds__(256) void k3_kpinv(
    const float* __restrict__ y1, const float* __restrict__ st_in,
    const float* __restrict__ q_pts, const float* __restrict__ s_pts,
    const int* __restrict__ idx, const float* __restrict__ kp,
    const float* __restrict__ g_u1, const float* __restrict__ b_u1,
    const float* __restrict__ w_g1, const float* __restrict__ b_g1,
    const float* __restrict__ w_g2, const float* __restrict__ b_g2,
    float* __restrict__ x2, float* __restrict__ st_out, int M)
{
    __shared__ float a1s[32], b1s[32];
    __shared__ float wg1s[32 * 8];     // [c][j]
    __shared__ float bg1s[8];
    __shared__ float wg2s[8 * 30];     // [j][l], l = k*2+g
    __shared__ float bg2s[30];
    __shared__ float kps[KP * 3];
    __shared__ int   ids[4][32];
    __shared__ float ctr[4][32];
    __shared__ float h1s[4][8];
    __shared__ float wks[4][30];
    __shared__ float ss[4][64];        // [g*32 + h]
    __shared__ float bsum[32], bsq[32];

    int t = threadIdx.x;
    if (t < 32) {
        float mean = st_in[t] * (1.0f / M);
        float var  = st_in[32 + t] * (1.0f / M) - mean * mean;
        float inv  = rsqrtf(var + EPS);
        float a = g_u1[t] * inv;
        a1s[t] = a;
        b1s[t] = b_u1[t] - mean * a;
        bsum[t] = 0.f; bsq[t] = 0.f;
    }
    wg1s[t] = w_g1[t];                 // exactly 256 elems
    if (t < 8)      bg1s[t] = b_g1[t];
    if (t < 240)    wg2s[t] = w_g2[t];
    if (t < 30)     bg2s[t] = b_g2[t];
    if (t < KP * 3) kps[t]  = kp[t];

    int wave = t >> 6, lane = t & 63;
    int m = blockIdx.x * 4 + wave;
    bool act = m < M;
    int p = lane >> 5;    // half: which 16 neighbors (and group g in phase 4)
    int c = lane & 31;    // channel (and neighbor h in phase 4)

    if (act && p == 0) ids[wave][c] = idx[m * HNB + c];
    __syncthreads();

    // Phase 1: gather + BN + lrelu + running max; v[i] kept in registers.
    float v[16];
    float cmax = -1e30f;
    if (act) {
        float a = a1s[c], bb = b1s[c];
#pragma unroll
        for (int i = 0; i < 16; ++i) {
            int n = ids[wave][2 * i + p];
            float x = y1[(size_t)n * CMID + c] * a + bb;
            x = x >= 0.f ? x : NEG * x;
            v[i] = x;
            cmax = fmaxf(cmax, x);
        }
    }
    cmax = fmaxf(cmax, __shfl_xor(cmax, 32, 64));
    if (act && p == 0) ctr[wave][c] = cmax;
    __syncthreads();

    // Phase 2: h1 = lrelu(center @ Wg1 + bg1), lanes 0..7 of each wave.
    if (act && lane < 8) {
        float acc = bg1s[lane];
#pragma unroll
        for (int cc = 0; cc < 32; ++cc)
            acc += ctr[wave][cc] * wg1s[cc * 8 + lane];
        h1s[wave][lane] = acc >= 0.f ? acc : NEG * acc;
    }
    __syncthreads();

    // Phase 3: w[l] = bg2[l] + h1 @ Wg2[:,l], lanes 0..29.
    if (act && lane < 30) {
        float acc = bg2s[lane];
#pragma unroll
        for (int j = 0; j < 8; ++j)
            acc += h1s[wave][j] * wg2s[j * 30 + lane];
        wks[wave][lane] = acc;
    }
    __syncthreads();

    // Phase 4: geometry + s[h][g]. lane = g*32 + h (g = p, h = c).
    if (act) {
        int h = c, g = p;
        int n = ids[wave][h];
        float qx = q_pts[m * 3 + 0], qy = q_pts[m * 3 + 1], qz = q_pts[m * 3 + 2];
        float dx = s_pts[n * 3 + 0] - qx;
        float dy = s_pts[n * 3 + 1] - qy;
        float dz = s_pts[n * 3 + 2] - qz;
        float sv = 0.f;
#pragma unroll
        for (int k = 0; k < KP; ++k) {
            float ex = dx - kps[k * 3 + 0];
            float ey = dy - kps[k * 3 + 1];
            float ez = dz - kps[k * 3 + 2];
            float d = sqrtf(ex * ex + ey * ey + ez * ez);
            float wk = 1.0f - d;
            wk = wk > 0.f ? wk : 0.f;
            sv += wk * wks[wave][k * 2 + g];
        }
        ss[wave][g * 32 + h] = sv;
    }
    __syncthreads();

    // Phase 5: out[c] = sum_h v[h][c] * s[h][g(c)], halves combined by xor-32.
    float acc = 0.f;
    if (act) {
        int g = c >> 4;
#pragma unroll
        for (int i = 0; i < 16; ++i)
            acc += v[i] * ss[wave][g * 32 + 2 * i + p];
    }
    acc += __shfl_xor(acc, 32, 64);
    if (act && p == 0) {
        x2[(size_t)m * CMID + c] = acc;
        atomicAdd(&bsum[c], acc);
        atomicAdd(&bsq[c], acc * acc);
    }
    __syncthreads();
    if (t < 32) { atomicAdd(&st_out[64 + t], bsum[t]); atomicAdd(&st_out[96 + t], bsq[t]); }
}

// ---------------------------------------------------------------------------
// K6: z = lrelu(bn_c(x2)) @ w_u2 on the fly; per-channel (128) sum/sumsq only.
// Register-blocked: thread = 4 consecutive outputs x 4 rows, float4 LDS reads.
// ---------------------------------------------------------------------------
__global__ __launch_bounds__(256) void k6_zstats(
    const float* __restrict__ x2, const float* __restrict__ w_u2,
    const float* __restrict__ g_c, const float* __restrict__ b_c,
    float* __restrict__ st, int M)
{
    __shared__ float Ws[CMID * CIN];   // [j][o] 16 KB
    __shared__ float S[32 * CMID];     // activated rows
    __shared__ float ac[32], bc[32];
    __shared__ float rsum[128], rsq[128];
    int t = threadIdx.x;
    for (int i = t; i < CMID * CIN; i += 256) Ws[i] = w_u2[i];
    if (t < 32) {
        float mean = st[64 + t] * (1.0f / M);
        float var  = st[96 + t] * (1.0f / M) - mean * mean;
        float inv  = rsqrtf(var + EPS);
        float a = g_c[t] * inv;
        ac[t] = a; bc[t] = b_c[t] - mean * a;
    }
    if (t < 128) { rsum[t] = 0.f; rsq[t] = 0.f; }
    int m0 = blockIdx.x * 32;
    int rows = min(32, M - m0);
    __syncthreads();
    for (int i = t; i < rows * CMID; i += 256) {
        int cch = i & 31;
        float x = x2[(size_t)m0 * CMID + i] * ac[cch] + bc[cch];
        S[i] = x >= 0.f ? x : NEG * x;
    }
    __syncthreads();
    int ob = (t & 31) * 4;
    float lsum[4] = {0,0,0,0}, lsq[4] = {0,0,0,0};
    for (int r = t >> 5; r < rows; r += 8) {
        float acc[4] = {0,0,0,0};
        for (int j4 = 0; j4 < 8; ++j4) {
            float4 s4 = *(const float4*)&S[r * CMID + j4 * 4];
            float sv[4] = {s4.x, s4.y, s4.z, s4.w};
#pragma unroll
            for (int u = 0; u < 4; ++u) {
                float4 w4 = *(const float4*)&Ws[(j4 * 4 + u) * CIN + ob];
                acc[0] += sv[u] * w4.x; acc[1] += sv[u] * w4.y;
                acc[2] += sv[u] * w4.z; acc[3] += sv[u] * w4.w;
            }
        }
#pragma unroll
        for (int u = 0; u < 4; ++u) { lsum[u] += acc[u]; lsq[u] += acc[u] * acc[u]; }
    }
#pragma unroll
    for (int u = 0; u < 4; ++u) { atomicAdd(&rsum[ob + u], lsum[u]); atomicAdd(&rsq[ob + u], lsq[u]); }
    __syncthreads();
    if (t < 128) { atomicAdd(&st[128 + t], rsum[t]); atomicAdd(&st[256 + t], rsq[t]); }
}

// ---------------------------------------------------------------------------
// K8: recompute z, bn_u2, + residual, lrelu -> out (M,128). Same blocking.
// ---------------------------------------------------------------------------
__global__ __launch_bounds__(256) void k8_final(
    const float* __restrict__ x2, const float* __restrict__ w_u2,
    const float* __restrict__ g_c, const float* __restrict__ b_c,
    const float* __restrict__ g_u2, const float* __restrict__ b_u2,
    const float* __restrict__ s_feats, const float* __restrict__ st,
    float* __restrict__ out, int M)
{
    __shared__ float Ws[CMID * CIN];
    __shared__ float S[32 * CMID];
    __shared__ float ac[32], bc[32];
    __shared__ float a2[128], b2[128];
    int t = threadIdx.x;
    for (int i = t; i < CMID * CIN; i += 256) Ws[i] = w_u2[i];
    if (t < 32) {
        float mean = st[64 + t] * (1.0f / M);
        float var  = st[96 + t] * (1.0f / M) - mean * mean;
        float inv  = rsqrtf(var + EPS);
        float a = g_c[t] * inv;
        ac[t] = a; bc[t] = b_c[t] - mean * a;
    }
    if (t < 128) {
        float mean = st[128 + t] * (1.0f / M);
        float var  = st[256 + t] * (1.0f / M) - mean * mean;
        float inv  = rsqrtf(var + EPS);
        float a = g_u2[t] * inv;
        a2[t] = a; b2[t] = b_u2[t] - mean * a;
    }
    int m0 = blockIdx.x * 32;
    int rows = min(32, M - m0);
    __syncthreads();
    for (int i = t; i < rows * CMID; i += 256) {
        int cch = i & 31;
        float x = x2[(size_t)m0 * CMID + i] * ac[cch] + bc[cch];
        S[i] = x >= 0.f ? x : NEG * x;
    }
    __syncthreads();
    int ob = (t & 31) * 4;
    for (int r = t >> 5; r < rows; r += 8) {
        float acc[4] = {0,0,0,0};
        for (int j4 = 0; j4 < 8; ++j4) {
            float4 s4 = *(const float4*)&S[r * CMID + j4 * 4];
            float sv[4] = {s4.x, s4.y, s4.z, s4.w};
#pragma unroll
            for (int u = 0; u < 4; ++u) {
                float4 w4 = *(const float4*)&Ws[(j4 * 4 + u) * CIN + ob];
                acc[0] += sv[u] * w4.x; acc[1] += sv[u] * w4.y;
                acc[2] += sv[u] * w4.z; acc[3] += sv[u] * w4.w;
            }
        }
        size_t gi = (size_t)(m0 + r) * CIN + ob;
        float4 sf = *(const float4*)&s_feats[gi];
        float o0 = acc[0] * a2[ob + 0] + b2[ob + 0] + sf.x;
        float o1 = acc[1] * a2[ob + 1] + b2[ob + 1] + sf.y;
        float o2 = acc[2] * a2[ob + 2] + b2[ob + 2] + sf.z;
        float o3 = acc[3] * a2[ob + 3] + b2[ob + 3] + sf.w;
        float4 o;
        o.x = o0 >= 0.f ? o0 : NEG * o0;
        o.y = o1 >= 0.f ? o1 : NEG * o1;
        o.z = o2 >= 0.f ? o2 : NEG * o2;
        o.w = o3 >= 0.f ? o3 : NEG * o3;
        *(float4*)&out[gi] = o;
    }
}

extern "C" void kernel_launch(void* const* d_in, const int* in_sizes, int n_in,
                              void* d_out, int out_size, void* d_ws, size_t ws_size,
                              hipStream_t stream) {
    const float* q_pts   = (const float*)d_in[0];
    const float* s_pts   = (const float*)d_in[1];
    const float* s_feats = (const float*)d_in[2];
    const int*   idx     = (const int*)d_in[3];
    const float* kp      = (const float*)d_in[4];
    const float* w_u1    = (const float*)d_in[5];
    const float* g_u1    = (const float*)d_in[6];
    const float* b_u1    = (const float*)d_in[7];
    const float* w_g1    = (const float*)d_in[8];
    const float* b_g1    = (const float*)d_in[9];
    const float* w_g2    = (const float*)d_in[10];
    const float* b_g2    = (const float*)d_in[11];
    const float* g_c     = (const float*)d_in[12];
    const float* b_c     = (const float*)d_in[13];
    const float* w_u2    = (const float*)d_in[14];
    const float* g_u2    = (const float*)d_in[15];
    const float* b_u2    = (const float*)d_in[16];

    int M = in_sizes[3] / HNB;   // 50000

    float* ws = (float*)d_ws;
    float* y1 = ws;                        // M*32
    float* x2 = ws + (size_t)M * CMID;     // M*32
    float* st = ws + (size_t)M * 2 * CMID; // 384 floats of stats

    hipMemsetAsync(st, 0, 384 * sizeof(float), stream);

    int nb = (M + 31) / 32;
    k1_gemm1<<<nb, 256, 0, stream>>>(s_feats, w_u1, y1, st, M);
    k3_kpinv<<<(M + 3) / 4, 256, 0, stream>>>(y1, st, q_pts, s_pts, idx, kp,
                                              g_u1, b_u1, w_g1, b_g1, w_g2, b_g2,
                                              x2, st, M);
    k6_zstats<<<nb, 256, 0, stream>>>(x2, w_u2, g_c, b_c, st, M);
    k8_final<<<nb, 256, 0, stream>>>(x2, w_u2, g_c, b_c, g_u2, b_u2,
                                     s_feats, st, (float*)d_out, M);
}